// Round 4
// baseline (169.339 us; speedup 1.0000x reference)
//
#include <hip/hip_runtime.h>
#include <math.h>

// ---- output layout ----
#define OFF_IMU  0
#define OFF_ATOM 19660800
#define OFF_SEG  20160000
#define OFF_FC   20659200
#define OFF_FL   20691968

// ---- ws layout (4-byte elements) ----
#define WS_BRIDGE 0        // 32768 floats  (8192 x 4)
#define WS_TR     32768    // 262144 floats (8192 x 32)
#define WS_SEGID  294912   // 8192 ints
#define WS_ENDS   303104   // 4160 ints
#define WS_STARTS 307264   // 4160 ints
#define WS_NK     311424   // 32 ints

static __device__ __forceinline__ int imin(int a, int b) { return a < b ? a : b; }
static __device__ __forceinline__ int imax(int a, int b) { return a > b ? a : b; }

// ============================================================================
// K1: conv1d(6->32,k=3,VALID) + ReLU + half-mean-pool + bridge sigmoid MLP
// 4096 blocks x 256 threads; 2 samples/block, 128 lanes/sample.
// Lane c (<100) owns t = 4c..4c+3 for ALL 32 oc: acc[32][2] statically indexed.
// x window (36 regs) loaded once from global; weights = wave-uniform LDS
// broadcasts (no per-lane weight residency -> no register blowup).
// ============================================================================
__global__ __launch_bounds__(256, 3) void k1_conv_bridge(
    const float* __restrict__ x, const float* __restrict__ conv_w,
    const float* __restrict__ conv_b, const float* __restrict__ W_b1,
    const float* __restrict__ b_b1, float* __restrict__ bridge)
{
    __shared__ float ws[32][20];       // [oc][ic*3+k]; [18]=0, [19]=bias
    __shared__ float part[2][64][9];   // [smp][oc*2+h][group], +1 pad
    const int tid = threadIdx.x;
    const int n0 = blockIdx.x * 2;

    if (tid < 32) {
        const float* wp = conv_w + tid * 18;
#pragma unroll
        for (int j = 0; j < 18; ++j) ws[tid][j] = wp[j];
        ws[tid][18] = 0.0f;
        ws[tid][19] = conv_b[tid];
    }
    __syncthreads();

    const int smp = tid >> 7;          // sample within block
    const int c   = tid & 127;         // t-chunk id; active c<100
    const bool act = c < 100;
    const int cc  = act ? c : 99;      // clamp for safe addressing
    const int t0  = c * 4;

    // load x[ic][t0..t0+5] into registers (coalesced: lanes stride 16B)
    const float* xb = x + (size_t)(n0 + smp) * 2400 + cc * 4;
    float xv[6][6];
#pragma unroll
    for (int ic = 0; ic < 6; ++ic) {
        const float4 a = *(const float4*)(xb + ic * 400);
        xv[ic][0] = a.x; xv[ic][1] = a.y; xv[ic][2] = a.z; xv[ic][3] = a.w;
        if (cc < 99) {
            const float2 b2 = *(const float2*)(xb + ic * 400 + 4);
            xv[ic][4] = b2.x; xv[ic][5] = b2.y;
        } else {                       // never reads past row end
            xv[ic][4] = 0.0f; xv[ic][5] = 0.0f;
        }
    }
    float f0[4], f1[4];                // pooling-half masks (0 for invalid t)
#pragma unroll
    for (int dt = 0; dt < 4; ++dt) {
        const int t = t0 + dt;
        f0[dt] = (act && t < 199) ? 1.0f : 0.0f;
        f1[dt] = (act && t >= 199 && t < 398) ? 1.0f : 0.0f;
    }

    float acc0[32], acc1[32];
#pragma unroll
    for (int o = 0; o < 32; ++o) { acc0[o] = 0.0f; acc1[o] = 0.0f; }

#pragma unroll
    for (int oc = 0; oc < 32; ++oc) {
        // wave-uniform broadcast reads: conflict-free, no residency cost
        const float4 wA = *(const float4*)&ws[oc][0];
        const float4 wB = *(const float4*)&ws[oc][4];
        const float4 wC = *(const float4*)&ws[oc][8];
        const float4 wD = *(const float4*)&ws[oc][12];
        const float4 wE = *(const float4*)&ws[oc][16];   // w16,w17,0,bias
        const float w[18] = {wA.x,wA.y,wA.z,wA.w, wB.x,wB.y,wB.z,wB.w,
                             wC.x,wC.y,wC.z,wC.w, wD.x,wD.y,wD.z,wD.w,
                             wE.x,wE.y};
        float s[4] = {wE.w, wE.w, wE.w, wE.w};
#pragma unroll
        for (int ic = 0; ic < 6; ++ic)
#pragma unroll
            for (int k = 0; k < 3; ++k) {
                const float wv = w[ic * 3 + k];
#pragma unroll
                for (int dt = 0; dt < 4; ++dt)
                    s[dt] = fmaf(wv, xv[ic][dt + k], s[dt]);
            }
#pragma unroll
        for (int dt = 0; dt < 4; ++dt) {
            const float r = fmaxf(s[dt], 0.0f);
            acc0[oc] = fmaf(r, f0[dt], acc0[oc]);
            acc1[oc] = fmaf(r, f1[dt], acc1[oc]);
        }
    }

    // 16-lane butterfly reduce over t-chunks
#pragma unroll
    for (int off = 1; off < 16; off <<= 1) {
#pragma unroll
        for (int o = 0; o < 32; ++o) {
            acc0[o] += __shfl_xor(acc0[o], off, 16);
            acc1[o] += __shfl_xor(acc1[o], off, 16);
        }
    }
    const int g = (tid & 127) >> 4;    // group 0..7 within sample
    if ((tid & 15) == 0) {             // static acc indices (rule #20)
#pragma unroll
        for (int o = 0; o < 32; ++o) {
            part[smp][o * 2 + 0][g] = acc0[o];
            part[smp][o * 2 + 1][g] = acc1[o];
        }
    }
    __syncthreads();
    if (tid < 128) {                   // wave = sample; lane f = feature
        const int s2 = tid >> 6, f = tid & 63;
        float v = 0.0f;
#pragma unroll
        for (int gg = 0; gg < 8; ++gg) v += part[s2][f][gg];
        v *= (1.0f / 199.0f);
        const float4 wb = *(const float4*)(W_b1 + f * 4);
        float p0 = v * wb.x, p1 = v * wb.y, p2 = v * wb.z, p3 = v * wb.w;
#pragma unroll
        for (int off = 1; off < 64; off <<= 1) {
            p0 += __shfl_xor(p0, off, 64);
            p1 += __shfl_xor(p1, off, 64);
            p2 += __shfl_xor(p2, off, 64);
            p3 += __shfl_xor(p3, off, 64);
        }
        if (f == 0) {
            float* bp = bridge + (size_t)(n0 + s2) * 4;
            bp[0] = 1.0f / (1.0f + __expf(-(p0 + b_b1[0])));
            bp[1] = 1.0f / (1.0f + __expf(-(p1 + b_b1[1])));
            bp[2] = 1.0f / (1.0f + __expf(-(p2 + b_b1[2])));
            bp[3] = 1.0f / (1.0f + __expf(-(p3 + b_b1[3])));
        }
    }
}

// ============================================================================
// K23: forcast + masked floss (to d_out) fused with per-batch segmentation.
// one block per b (32 x 256)
// ============================================================================
__global__ __launch_bounds__(256) void k23_forcast_seg(
    const float* __restrict__ bridge, const float* __restrict__ imu_mask,
    const float* __restrict__ W_fc, const float* __restrict__ b_fc,
    const int* __restrict__ imu_len, float* __restrict__ out,
    int* __restrict__ segid_ws, int* __restrict__ ends_ws,
    int* __restrict__ starts_ws, int* __restrict__ nk_ws)
{
    const int b = blockIdx.x, tid = threadIdx.x;
    const int n = b * 256 + tid;
    __shared__ float fl[256];
    __shared__ float sel[256];
    __shared__ float sp[256];
    __shared__ int pk[256];
    __shared__ int sc[2][256];
    __shared__ int kpl[256];

    // ---- forcast + floss ----
    float sh[4], cur[4];
#pragma unroll
    for (int j = 0; j < 4; ++j) {
        sh[j] = (tid == 0) ? 0.0f : bridge[(n - 1) * 4 + j];
        cur[j] = bridge[n * 4 + j];
    }
    const float fm = ((tid == 0) ? 0.0f : 1.0f) * imu_mask[n];
    float flv = 0.0f;
#pragma unroll
    for (int j = 0; j < 4; ++j) {
        float f = b_fc[j];
#pragma unroll
        for (int i = 0; i < 4; ++i) f = fmaf(sh[i], W_fc[i * 4 + j], f);
        out[OFF_FC + n * 4 + j] = f;
        const float d = (f - cur[j]) * fm;
        flv = fmaf(d, d, flv);
    }
    flv *= 0.25f;
    const bool lm = (tid >= 2) && (tid < 254);
    flv = (flv > 0.001f && lm) ? flv : 0.0f;
    out[OFF_FL + n] = flv;

    // ---- segmentation ----
    fl[tid] = flv;
    sp[tid] = 0.0f;
    __syncthreads();
    if (tid < 64) {                       // sel: windows of 4, first-max
        const int base = tid * 4;
        float m = fl[base]; int idx = 0;
#pragma unroll
        for (int i = 1; i < 4; ++i) { float v = fl[base + i]; if (v > m) { m = v; idx = i; } }
#pragma unroll
        for (int i = 0; i < 4; ++i) sel[base + i] = (i == idx) ? m : 0.0f;
    }
    __syncthreads();
    if (tid < 63) {                       // sel2 on sel[2:254), 63 windows of 4
        const int base = 2 + tid * 4;
        float m = sel[base]; int idx = 0;
#pragma unroll
        for (int i = 1; i < 4; ++i) { float v = sel[base + i]; if (v > m) { m = v; idx = i; } }
        sp[base + idx] = (m > 0.0f) ? 1.0f : 0.0f;
    }
    __syncthreads();
    int last = (int)rintf((float)imu_len[b] * (1.0f / 256.0f));  // half-even
    last = imin(imax(last, 2), 256);
    const int point = ((sp[tid] > 0.0f) && (tid < last)) ? 1 : 0;
    pk[tid] = point;
    __syncthreads();
    const int pnext = (tid < 255) ? pk[tid + 1] : 0;
    const int bnd = pnext | ((tid + 1 == last) ? 1 : 0);
    const int kept = (point && !bnd) ? 1 : 0;
    __syncthreads();
    sc[0][tid] = kept;
    __syncthreads();
    int src = 0;                          // Hillis-Steele inclusive scan
    for (int off = 1; off < 256; off <<= 1) {
        const int v = sc[src][tid] + ((tid >= off) ? sc[src][tid - off] : 0);
        sc[src ^ 1][tid] = v;
        __syncthreads();
        src ^= 1;
    }
    const int myid = sc[src][tid];
    segid_ws[b * 256 + tid] = myid;
    const int nk = sc[src][255];
    if (kept) kpl[myid - 1] = tid;
    __syncthreads();
    if (tid < 130) {
        ends_ws[b * 130 + tid] = (tid < nk) ? kpl[tid] : last;
        starts_ws[b * 130 + tid] = (tid == 0) ? 0 : ((tid - 1 < nk) ? kpl[tid - 1] : last);
    }
    if (tid == 0) nk_ws[b] = nk;
}

// ============================================================================
// K4: segment-masked attention (DM=4, 2 heads) + transformer block + tr_out
// grid 256 = (b, 32-query chunk), 256 threads: 8 j-groups x 32 queries,
// LDS online-softmax merge. NOTE hb[b,s] = bridge[s*32 + b] (scrambled).
// exp() only evaluated with argument <= 0 (select, never mask-multiply).
// ============================================================================
__global__ __launch_bounds__(256) void k4_attn(
    const float* __restrict__ bridge, const int* __restrict__ segid_ws,
    const int* __restrict__ imu_len,
    const float* __restrict__ Wqkv, const float* __restrict__ Wo,
    const float* __restrict__ ln1_g, const float* __restrict__ ln1_b,
    const float* __restrict__ Wf1, const float* __restrict__ bf1,
    const float* __restrict__ Wf2, const float* __restrict__ bf2,
    const float* __restrict__ ln2_g, const float* __restrict__ ln2_b,
    const float* __restrict__ Wout, const float* __restrict__ bout,
    float* __restrict__ tr_ws)
{
    const int b = blockIdx.x >> 3;
    const int chunk = blockIdx.x & 7;
    const int tid = threadIdx.x;
    __shared__ float kv[256][8];
    __shared__ int sid[256];
    __shared__ float part[32][8][8];
    {
        const int s2 = tid;
        const float4 h = *(const float4*)(bridge + (size_t)(s2 * 32 + b) * 4);
#pragma unroll
        for (int e = 0; e < 4; ++e) {
            kv[s2][e]     = h.x * Wqkv[16 + e] + h.y * Wqkv[20 + e] + h.z * Wqkv[24 + e] + h.w * Wqkv[28 + e];
            kv[s2][4 + e] = h.x * Wqkv[32 + e] + h.y * Wqkv[36 + e] + h.z * Wqkv[40 + e] + h.w * Wqkv[44 + e];
        }
        sid[s2] = segid_ws[b * 256 + s2];
    }
    __syncthreads();
    int last = (int)rintf((float)imu_len[b] * (1.0f / 256.0f));
    last = imin(imax(last, 2), 256);
    const int lq = tid & 31;
    const int jg = tid >> 5;
    const int sq = chunk * 32 + lq;
    {
        const float4 h = *(const float4*)(bridge + (size_t)(sq * 32 + b) * 4);
        float q[4];
#pragma unroll
        for (int e = 0; e < 4; ++e)
            q[e] = h.x * Wqkv[e] + h.y * Wqkv[4 + e] + h.z * Wqkv[8 + e] + h.w * Wqkv[12 + e];
        const bool vs = sq < last;
        const int ms = sid[sq];
        const float isq = 0.70710678118654752f;
        float m0 = -1e30f, l0 = 0.f, a00 = 0.f, a01 = 0.f;
        float m1 = -1e30f, l1 = 0.f, a10 = 0.f, a11 = 0.f;
#pragma unroll 4
        for (int jj = 0; jj < 32; ++jj) {
            const int j = jg * 32 + jj;
            const bool allowed = (j == sq) || (vs && (j < last) && (sid[j] == ms));
            const float sc0 = (q[0] * kv[j][0] + q[1] * kv[j][1]) * isq;
            const float sc1 = (q[2] * kv[j][2] + q[3] * kv[j][3]) * isq;
            {
                const float mn = allowed ? fmaxf(m0, sc0) : m0;
                const float c = __expf(m0 - mn);                      // arg <= 0 always
                const float e = allowed ? __expf(sc0 - mn) : 0.0f;    // select: no inf*0
                l0 = l0 * c + e; a00 = a00 * c + e * kv[j][4]; a01 = a01 * c + e * kv[j][5]; m0 = mn;
            }
            {
                const float mn = allowed ? fmaxf(m1, sc1) : m1;
                const float c = __expf(m1 - mn);
                const float e = allowed ? __expf(sc1 - mn) : 0.0f;
                l1 = l1 * c + e; a10 = a10 * c + e * kv[j][6]; a11 = a11 * c + e * kv[j][7]; m1 = mn;
            }
        }
        float* pp = part[lq][jg];
        pp[0] = m0; pp[1] = l0; pp[2] = a00; pp[3] = a01;
        pp[4] = m1; pp[5] = l1; pp[6] = a10; pp[7] = a11;
    }
    __syncthreads();
    if (tid < 32) {
        const int s = chunk * 32 + tid;
        float M0 = -1e30f, L0 = 0.f, A00 = 0.f, A01 = 0.f;
        float M1 = -1e30f, L1 = 0.f, A10 = 0.f, A11 = 0.f;
#pragma unroll
        for (int p = 0; p < 8; ++p) {
            const float* pp = part[tid][p];
            {
                const float mn = fmaxf(M0, pp[0]);
                const float c0 = __expf(M0 - mn), c1 = __expf(pp[0] - mn);   // args <= 0
                L0 = L0 * c0 + pp[1] * c1; A00 = A00 * c0 + pp[2] * c1; A01 = A01 * c0 + pp[3] * c1; M0 = mn;
            }
            {
                const float mn = fmaxf(M1, pp[4]);
                const float c0 = __expf(M1 - mn), c1 = __expf(pp[4] - mn);
                L1 = L1 * c0 + pp[5] * c1; A10 = A10 * c0 + pp[6] * c1; A11 = A11 * c0 + pp[7] * c1; M1 = mn;
            }
        }
        const float4 h = *(const float4*)(bridge + (size_t)(s * 32 + b) * 4);
        const float hb0 = h.x, hb1 = h.y, hb2 = h.z, hb3 = h.w;
        float ao[4] = {A00 / L0, A01 / L0, A10 / L1, A11 / L1};
        float x1[4];
#pragma unroll
        for (int jj = 0; jj < 4; ++jj)
            x1[jj] = ao[0] * Wo[jj] + ao[1] * Wo[4 + jj] + ao[2] * Wo[8 + jj] + ao[3] * Wo[12 + jj];
        x1[0] += hb0; x1[1] += hb1; x1[2] += hb2; x1[3] += hb3;
        float mean = 0.25f * (x1[0] + x1[1] + x1[2] + x1[3]);
        float var = 0.f;
#pragma unroll
        for (int i = 0; i < 4; ++i) { float d = x1[i] - mean; var += d * d; }
        var *= 0.25f;
        const float rs1 = rsqrtf(var + 1e-5f);
        float h1v[4];
#pragma unroll
        for (int i = 0; i < 4; ++i) h1v[i] = (x1[i] - mean) * rs1 * ln1_g[i] + ln1_b[i];
        float o2[4] = {bf2[0], bf2[1], bf2[2], bf2[3]};
#pragma unroll
        for (int kk = 0; kk < 16; ++kk) {
            float t = bf1[kk];
#pragma unroll
            for (int i = 0; i < 4; ++i) t = fmaf(h1v[i], Wf1[i * 16 + kk], t);
            t = fmaxf(t, 0.0f);
#pragma unroll
            for (int jj = 0; jj < 4; ++jj) o2[jj] = fmaf(t, Wf2[kk * 4 + jj], o2[jj]);
        }
        float x2[4];
#pragma unroll
        for (int i = 0; i < 4; ++i) x2[i] = h1v[i] + o2[i];
        float mean2 = 0.25f * (x2[0] + x2[1] + x2[2] + x2[3]);
        float var2 = 0.f;
#pragma unroll
        for (int i = 0; i < 4; ++i) { float d = x2[i] - mean2; var2 += d * d; }
        var2 *= 0.25f;
        const float rs2 = rsqrtf(var2 + 1e-5f);
        float h2v[4];
#pragma unroll
        for (int i = 0; i < 4; ++i) h2v[i] = (x2[i] - mean2) * rs2 * ln2_g[i] + ln2_b[i];
        float* tp = tr_ws + ((size_t)(b * 256 + s)) * 32;
#pragma unroll
        for (int mm = 0; mm < 32; ++mm)
            tp[mm] = bout[mm] + h2v[0] * Wout[mm] + h2v[1] * Wout[32 + mm]
                   + h2v[2] * Wout[64 + mm] + h2v[3] * Wout[96 + mm];
    }
}

// ============================================================================
// K5: atoms: atom_gen = (emb @ Wa + ba)*valid ; seg_interp gather from x
// grid (130, 32), 128 threads (120 active: d*20+i)
// ============================================================================
__global__ __launch_bounds__(128) void k5_atoms(
    const float* __restrict__ x, const float* __restrict__ tr_ws,
    const int* __restrict__ ends_ws, const int* __restrict__ starts_ws,
    const int* __restrict__ nk_ws,
    const float* __restrict__ Wa, const float* __restrict__ ba,
    float* __restrict__ out)
{
    const int a = blockIdx.x;
    const int b = blockIdx.y;
    const int tid = threadIdx.x;
    __shared__ float emb[32];
    const int e = ends_ws[b * 130 + a];
    const int st = starts_ws[b * 130 + a];
    const int nk = nk_ws[b];
    const float valid = (a <= nk) ? 1.0f : 0.0f;
    const int ec = imin(imax(e - 1, 0), 255);
    if (tid < 32) emb[tid] = tr_ws[((size_t)(b * 256 + ec)) * 32 + tid];
    __syncthreads();
    if (tid < 120) {
        float v = ba[tid];
#pragma unroll
        for (int f = 0; f < 32; ++f) v = fmaf(emb[f], Wa[f * 120 + tid], v);
        out[OFF_ATOM + ((size_t)(b * 130 + a)) * 120 + tid] = v * valid;
        const int d = tid / 20, i = tid % 20;
        const int ilen = (e - st) * 400;
        int idx = st * 400 + (i * ilen) / 20;
        idx = imin(imax(idx, 0), 102399);
        const int si = idx / 400, ti = idx % 400;
        const float px = x[(((size_t)b * 256 + si) * 6 + d) * 400 + ti];
        out[OFF_SEG + ((size_t)(b * 130 + a)) * 120 + tid] = px * valid;
    }
}

// ============================================================================
// K6: imu_gen GEMM: relu(bridge@Wd1+bd1) @ Wd2(64x2400) + bd2
// grid (256 n-tiles of 32, 10 m-tiles of 256), 256 threads, 8x4 micro-tile
// ============================================================================
__global__ __launch_bounds__(256) void k6_imu(
    const float* __restrict__ bridge, const float* __restrict__ Wd1,
    const float* __restrict__ bd1, const float* __restrict__ Wd2,
    const float* __restrict__ bd2, float* __restrict__ out)
{
    __shared__ float hl[64 * 32];     // [f][i]
    const int n0 = blockIdx.x * 32;
    const int mb = blockIdx.y;
    const int tid = threadIdx.x;
    for (int e = tid; e < 2048; e += 256) {
        const int f = e >> 5, i = e & 31;
        const float4 br = *(const float4*)(bridge + (size_t)(n0 + i) * 4);
        const float v = bd1[f] + br.x * Wd1[f] + br.y * Wd1[64 + f]
                      + br.z * Wd1[128 + f] + br.w * Wd1[192 + f];
        hl[f * 32 + i] = fmaxf(v, 0.0f);
    }
    __syncthreads();
    const int gm = tid & 63, gn = tid >> 6;
    const int m0 = mb * 256 + gm * 4;
    if (m0 >= 2400) return;
    float acc[8][4];
#pragma unroll
    for (int r = 0; r < 8; ++r)
#pragma unroll
        for (int c = 0; c < 4; ++c) acc[r][c] = 0.f;
#pragma unroll 4
    for (int f = 0; f < 64; ++f) {
        const float4 w4 = *(const float4*)&Wd2[(size_t)f * 2400 + m0];
        const float4 h0 = *(const float4*)&hl[f * 32 + gn * 8];
        const float4 h1 = *(const float4*)&hl[f * 32 + gn * 8 + 4];
        const float hv[8] = {h0.x, h0.y, h0.z, h0.w, h1.x, h1.y, h1.z, h1.w};
        const float wv[4] = {w4.x, w4.y, w4.z, w4.w};
#pragma unroll
        for (int r = 0; r < 8; ++r)
#pragma unroll
            for (int c = 0; c < 4; ++c) acc[r][c] = fmaf(hv[r], wv[c], acc[r][c]);
    }
    const float4 bb = *(const float4*)&bd2[m0];
#pragma unroll
    for (int r = 0; r < 8; ++r) {
        float4 o;
        o.x = acc[r][0] + bb.x; o.y = acc[r][1] + bb.y;
        o.z = acc[r][2] + bb.z; o.w = acc[r][3] + bb.w;
        *(float4*)&out[OFF_IMU + (size_t)(n0 + gn * 8 + r) * 2400 + m0] = o;
    }
}

// ============================================================================
extern "C" void kernel_launch(void* const* d_in, const int* in_sizes, int n_in,
                              void* d_out, int out_size, void* d_ws, size_t ws_size,
                              hipStream_t stream)
{
    const float* x        = (const float*)d_in[0];
    const float* imu_mask = (const float*)d_in[1];
    const int*   imu_len  = (const int*)  d_in[2];
    const float* conv_w   = (const float*)d_in[3];
    const float* conv_b   = (const float*)d_in[4];
    const float* W_b1     = (const float*)d_in[5];
    const float* b_b1     = (const float*)d_in[6];
    const float* W_fc     = (const float*)d_in[7];
    const float* b_fc     = (const float*)d_in[8];
    const float* Wqkv     = (const float*)d_in[9];
    const float* Wo       = (const float*)d_in[10];
    const float* ln1_g    = (const float*)d_in[11];
    const float* ln1_b    = (const float*)d_in[12];
    const float* Wf1      = (const float*)d_in[13];
    const float* bf1      = (const float*)d_in[14];
    const float* Wf2      = (const float*)d_in[15];
    const float* bf2      = (const float*)d_in[16];
    const float* ln2_g    = (const float*)d_in[17];
    const float* ln2_b    = (const float*)d_in[18];
    const float* Wout     = (const float*)d_in[19];
    const float* bout     = (const float*)d_in[20];
    const float* Wd1      = (const float*)d_in[21];
    const float* bd1      = (const float*)d_in[22];
    const float* Wd2      = (const float*)d_in[23];
    const float* bd2      = (const float*)d_in[24];
    const float* Wa       = (const float*)d_in[25];
    const float* ba       = (const float*)d_in[26];

    float* out = (float*)d_out;
    float* wsf = (float*)d_ws;
    int*   wsi = (int*)d_ws;

    float* bridge = wsf + WS_BRIDGE;
    float* tr_ws  = wsf + WS_TR;
    int* segid  = wsi + WS_SEGID;
    int* ends   = wsi + WS_ENDS;
    int* starts = wsi + WS_STARTS;
    int* nk     = wsi + WS_NK;

    k1_conv_bridge<<<4096, 256, 0, stream>>>(x, conv_w, conv_b, W_b1, b_b1, bridge);
    k23_forcast_seg<<<32, 256, 0, stream>>>(bridge, imu_mask, W_fc, b_fc, imu_len,
                                            out, segid, ends, starts, nk);
    k4_attn<<<256, 256, 0, stream>>>(bridge, segid, imu_len, Wqkv, Wo, ln1_g, ln1_b,
                                     Wf1, bf1, Wf2, bf2, ln2_g, ln2_b, Wout, bout, tr_ws);
    k5_atoms<<<dim3(130, 32), 128, 0, stream>>>(x, tr_ws, ends, starts, nk, Wa, ba, out);
    k6_imu<<<dim3(256, 10), 256, 0, stream>>>(bridge, Wd1, bd1, Wd2, bd2, out);
}

// Round 5
// 122.926 us; speedup vs baseline: 1.3776x; 1.3776x over previous
//
#include <hip/hip_runtime.h>
#include <math.h>

// ---- output layout ----
#define OFF_IMU  0
#define OFF_ATOM 19660800
#define OFF_SEG  20160000
#define OFF_FC   20659200
#define OFF_FL   20691968

// ---- ws layout (4-byte elements) ----
#define WS_BRIDGE 0        // 32768 floats  (8192 x 4)
#define WS_TR     32768    // 262144 floats (8192 x 32)
#define WS_SEGID  294912   // 8192 ints
#define WS_ENDS   303104   // 4160 ints
#define WS_STARTS 307264   // 4160 ints
#define WS_NK     311424   // 32 ints

static __device__ __forceinline__ int imin(int a, int b) { return a < b ? a : b; }
static __device__ __forceinline__ int imax(int a, int b) { return a > b ? a : b; }

// ============================================================================
// K1: conv1d(6->32,k=3,VALID) + ReLU + half-mean-pool + bridge sigmoid MLP
// 2048 blocks x 256 threads; 4 samples/block, one WAVE per sample.
// Lane l: oc = l&31, half = l>>5. Lane walks its half's 50 aligned 4-chunks,
// accumulating its own (oc,half) pooled sum -> NO cross-lane t-reduction.
// x reads are 2-address wave broadcasts from LDS (conflict-free).
// Per-lane state ~45 VGPR (w[18]+acc+window) -> no spills.
// ============================================================================
__global__ __launch_bounds__(256) void k1_conv_bridge(
    const float* __restrict__ x, const float* __restrict__ conv_w,
    const float* __restrict__ conv_b, const float* __restrict__ W_b1,
    const float* __restrict__ b_b1, float* __restrict__ bridge)
{
    __shared__ __align__(16) float xs[4][2424];  // [smp][ic*404 + t]; 400..403 zeroed
    __shared__ float pooledL[4][64];
    const int tid = threadIdx.x;
    const int n0 = blockIdx.x * 4;

    const int wv = tid >> 6;           // wave = sample
    const int l  = tid & 63;
    const int oc = l & 31;
    const int hg = l >> 5;             // pooling half

    // per-lane weights (one oc): 18 + bias, loaded once from global (L2-hot)
    float w[18];
    {
        const float* wp = conv_w + oc * 18;
#pragma unroll
        for (int j = 0; j < 18; ++j) w[j] = wp[j];
    }
    const float cb = conv_b[oc];

    // stage 4 samples of x into LDS (coalesced float4)
    const float* xn = x + (size_t)n0 * 2400;
    for (int i = tid; i < 2400; i += 256) {
        const float4 v = ((const float4*)xn)[i];
        const int smp = i / 600;
        const int r = i - smp * 600;
        const int ic = r / 100, t4 = (r - ic * 100) * 4;
        *(float4*)&xs[smp][ic * 404 + t4] = v;
    }
    if (tid < 96) {                    // zero pads so tail multiplies stay finite
        const int smp = tid / 24, r = tid - smp * 24;
        xs[smp][(r >> 2) * 404 + 400 + (r & 3)] = 0.0f;
    }
    __syncthreads();

    const float* xsm = xs[wv];
    const int tbase = hg * 200;        // half's first t (chunks of 4)
    float accMain = 0.0f;

    // body: 49 unmasked chunks (all positions strictly inside this half)
    for (int tc = 0; tc < 49; ++tc) {
        const int t0 = tbase + tc * 4;
        float s0 = cb, s1 = cb, s2 = cb, s3 = cb;
#pragma unroll
        for (int ic = 0; ic < 6; ++ic) {
            const float4 a  = *(const float4*)&xsm[ic * 404 + t0];
            const float2 b2 = *(const float2*)&xsm[ic * 404 + t0 + 4];
            const float x0 = a.x, x1 = a.y, x2 = a.z, x3 = a.w, x4 = b2.x, x5 = b2.y;
            const float w0 = w[ic * 3 + 0], w1 = w[ic * 3 + 1], w2 = w[ic * 3 + 2];
            s0 = fmaf(w0, x0, s0); s0 = fmaf(w1, x1, s0); s0 = fmaf(w2, x2, s0);
            s1 = fmaf(w0, x1, s1); s1 = fmaf(w1, x2, s1); s1 = fmaf(w2, x3, s1);
            s2 = fmaf(w0, x2, s2); s2 = fmaf(w1, x3, s2); s2 = fmaf(w2, x4, s2);
            s3 = fmaf(w0, x3, s3); s3 = fmaf(w1, x4, s3); s3 = fmaf(w2, x5, s3);
        }
        accMain += fmaxf(s0, 0.0f) + fmaxf(s1, 0.0f)
                 + fmaxf(s2, 0.0f) + fmaxf(s3, 0.0f);
    }

    // tail chunk tc=49: hg0 t=196..199 (196-198 -> half0, 199 -> half1 extra);
    //                   hg1 t=396..399 (396,397 valid; 398,399 masked; pad=0)
    float accExtra;
    {
        const int t0 = tbase + 196;
        float s0 = cb, s1 = cb, s2 = cb, s3 = cb;
#pragma unroll
        for (int ic = 0; ic < 6; ++ic) {
            const float4 a  = *(const float4*)&xsm[ic * 404 + t0];
            const float2 b2 = *(const float2*)&xsm[ic * 404 + t0 + 4];
            const float x0 = a.x, x1 = a.y, x2 = a.z, x3 = a.w, x4 = b2.x, x5 = b2.y;
            const float w0 = w[ic * 3 + 0], w1 = w[ic * 3 + 1], w2 = w[ic * 3 + 2];
            s0 = fmaf(w0, x0, s0); s0 = fmaf(w1, x1, s0); s0 = fmaf(w2, x2, s0);
            s1 = fmaf(w0, x1, s1); s1 = fmaf(w1, x2, s1); s1 = fmaf(w2, x3, s1);
            s2 = fmaf(w0, x2, s2); s2 = fmaf(w1, x3, s2); s2 = fmaf(w2, x4, s2);
            s3 = fmaf(w0, x3, s3); s3 = fmaf(w1, x4, s3); s3 = fmaf(w2, x5, s3);
        }
        const float r0 = fmaxf(s0, 0.0f), r1 = fmaxf(s1, 0.0f);
        const float r2 = fmaxf(s2, 0.0f), r3 = fmaxf(s3, 0.0f);
        accMain += r0 + r1 + (hg ? 0.0f : r2);   // hg1: t=398,399 invalid
        accExtra = hg ? 0.0f : r3;               // hg0: t=199 belongs to half1
    }

    // boundary fix: half1 total = accMain(hg1) + accExtra(hg0 partner)
    const float extraP = __shfl_xor(accExtra, 32);
    const float h = (hg ? (accMain + extraP) : accMain) * (1.0f / 199.0f);
    pooledL[wv][(oc << 1) | hg] = h;
    __syncthreads();

    // bridge MLP: all 256 threads; sample = tid>>6, feature f = tid&63
    {
        const int s2 = tid >> 6, f = tid & 63;
        const float v = pooledL[s2][f];
        const float4 wb = *(const float4*)(W_b1 + f * 4);
        float p0 = v * wb.x, p1 = v * wb.y, p2 = v * wb.z, p3 = v * wb.w;
#pragma unroll
        for (int off = 1; off < 64; off <<= 1) {
            p0 += __shfl_xor(p0, off, 64);
            p1 += __shfl_xor(p1, off, 64);
            p2 += __shfl_xor(p2, off, 64);
            p3 += __shfl_xor(p3, off, 64);
        }
        if (f == 0) {
            float* bp = bridge + (size_t)(n0 + s2) * 4;
            bp[0] = 1.0f / (1.0f + __expf(-(p0 + b_b1[0])));
            bp[1] = 1.0f / (1.0f + __expf(-(p1 + b_b1[1])));
            bp[2] = 1.0f / (1.0f + __expf(-(p2 + b_b1[2])));
            bp[3] = 1.0f / (1.0f + __expf(-(p3 + b_b1[3])));
        }
    }
}

// ============================================================================
// K23: forcast + masked floss (to d_out) fused with per-batch segmentation.
// one block per b (32 x 256)
// ============================================================================
__global__ __launch_bounds__(256) void k23_forcast_seg(
    const float* __restrict__ bridge, const float* __restrict__ imu_mask,
    const float* __restrict__ W_fc, const float* __restrict__ b_fc,
    const int* __restrict__ imu_len, float* __restrict__ out,
    int* __restrict__ segid_ws, int* __restrict__ ends_ws,
    int* __restrict__ starts_ws, int* __restrict__ nk_ws)
{
    const int b = blockIdx.x, tid = threadIdx.x;
    const int n = b * 256 + tid;
    __shared__ float fl[256];
    __shared__ float sel[256];
    __shared__ float sp[256];
    __shared__ int pk[256];
    __shared__ int sc[2][256];
    __shared__ int kpl[256];

    // ---- forcast + floss ----
    float sh[4], cur[4];
#pragma unroll
    for (int j = 0; j < 4; ++j) {
        sh[j] = (tid == 0) ? 0.0f : bridge[(n - 1) * 4 + j];
        cur[j] = bridge[n * 4 + j];
    }
    const float fm = ((tid == 0) ? 0.0f : 1.0f) * imu_mask[n];
    float flv = 0.0f;
#pragma unroll
    for (int j = 0; j < 4; ++j) {
        float f = b_fc[j];
#pragma unroll
        for (int i = 0; i < 4; ++i) f = fmaf(sh[i], W_fc[i * 4 + j], f);
        out[OFF_FC + n * 4 + j] = f;
        const float d = (f - cur[j]) * fm;
        flv = fmaf(d, d, flv);
    }
    flv *= 0.25f;
    const bool lm = (tid >= 2) && (tid < 254);
    flv = (flv > 0.001f && lm) ? flv : 0.0f;
    out[OFF_FL + n] = flv;

    // ---- segmentation ----
    fl[tid] = flv;
    sp[tid] = 0.0f;
    __syncthreads();
    if (tid < 64) {                       // sel: windows of 4, first-max
        const int base = tid * 4;
        float m = fl[base]; int idx = 0;
#pragma unroll
        for (int i = 1; i < 4; ++i) { float v = fl[base + i]; if (v > m) { m = v; idx = i; } }
#pragma unroll
        for (int i = 0; i < 4; ++i) sel[base + i] = (i == idx) ? m : 0.0f;
    }
    __syncthreads();
    if (tid < 63) {                       // sel2 on sel[2:254), 63 windows of 4
        const int base = 2 + tid * 4;
        float m = sel[base]; int idx = 0;
#pragma unroll
        for (int i = 1; i < 4; ++i) { float v = sel[base + i]; if (v > m) { m = v; idx = i; } }
        sp[base + idx] = (m > 0.0f) ? 1.0f : 0.0f;
    }
    __syncthreads();
    int last = (int)rintf((float)imu_len[b] * (1.0f / 256.0f));  // half-even
    last = imin(imax(last, 2), 256);
    const int point = ((sp[tid] > 0.0f) && (tid < last)) ? 1 : 0;
    pk[tid] = point;
    __syncthreads();
    const int pnext = (tid < 255) ? pk[tid + 1] : 0;
    const int bnd = pnext | ((tid + 1 == last) ? 1 : 0);
    const int kept = (point && !bnd) ? 1 : 0;
    __syncthreads();
    sc[0][tid] = kept;
    __syncthreads();
    int src = 0;                          // Hillis-Steele inclusive scan
    for (int off = 1; off < 256; off <<= 1) {
        const int v = sc[src][tid] + ((tid >= off) ? sc[src][tid - off] : 0);
        sc[src ^ 1][tid] = v;
        __syncthreads();
        src ^= 1;
    }
    const int myid = sc[src][tid];
    segid_ws[b * 256 + tid] = myid;
    const int nk = sc[src][255];
    if (kept) kpl[myid - 1] = tid;
    __syncthreads();
    if (tid < 130) {
        ends_ws[b * 130 + tid] = (tid < nk) ? kpl[tid] : last;
        starts_ws[b * 130 + tid] = (tid == 0) ? 0 : ((tid - 1 < nk) ? kpl[tid - 1] : last);
    }
    if (tid == 0) nk_ws[b] = nk;
}

// ============================================================================
// K4: segment-masked attention (DM=4, 2 heads) + transformer block + tr_out
// grid 256 = (b, 32-query chunk), 256 threads: 8 j-groups x 32 queries,
// LDS online-softmax merge. NOTE hb[b,s] = bridge[s*32 + b] (scrambled).
// exp() only evaluated with argument <= 0 (select, never mask-multiply).
// ============================================================================
__global__ __launch_bounds__(256) void k4_attn(
    const float* __restrict__ bridge, const int* __restrict__ segid_ws,
    const int* __restrict__ imu_len,
    const float* __restrict__ Wqkv, const float* __restrict__ Wo,
    const float* __restrict__ ln1_g, const float* __restrict__ ln1_b,
    const float* __restrict__ Wf1, const float* __restrict__ bf1,
    const float* __restrict__ Wf2, const float* __restrict__ bf2,
    const float* __restrict__ ln2_g, const float* __restrict__ ln2_b,
    const float* __restrict__ Wout, const float* __restrict__ bout,
    float* __restrict__ tr_ws)
{
    const int b = blockIdx.x >> 3;
    const int chunk = blockIdx.x & 7;
    const int tid = threadIdx.x;
    __shared__ float kv[256][8];
    __shared__ int sid[256];
    __shared__ float part[32][8][8];
    {
        const int s2 = tid;
        const float4 h = *(const float4*)(bridge + (size_t)(s2 * 32 + b) * 4);
#pragma unroll
        for (int e = 0; e < 4; ++e) {
            kv[s2][e]     = h.x * Wqkv[16 + e] + h.y * Wqkv[20 + e] + h.z * Wqkv[24 + e] + h.w * Wqkv[28 + e];
            kv[s2][4 + e] = h.x * Wqkv[32 + e] + h.y * Wqkv[36 + e] + h.z * Wqkv[40 + e] + h.w * Wqkv[44 + e];
        }
        sid[s2] = segid_ws[b * 256 + s2];
    }
    __syncthreads();
    int last = (int)rintf((float)imu_len[b] * (1.0f / 256.0f));
    last = imin(imax(last, 2), 256);
    const int lq = tid & 31;
    const int jg = tid >> 5;
    const int sq = chunk * 32 + lq;
    {
        const float4 h = *(const float4*)(bridge + (size_t)(sq * 32 + b) * 4);
        float q[4];
#pragma unroll
        for (int e = 0; e < 4; ++e)
            q[e] = h.x * Wqkv[e] + h.y * Wqkv[4 + e] + h.z * Wqkv[8 + e] + h.w * Wqkv[12 + e];
        const bool vs = sq < last;
        const int ms = sid[sq];
        const float isq = 0.70710678118654752f;
        float m0 = -1e30f, l0 = 0.f, a00 = 0.f, a01 = 0.f;
        float m1 = -1e30f, l1 = 0.f, a10 = 0.f, a11 = 0.f;
#pragma unroll 4
        for (int jj = 0; jj < 32; ++jj) {
            const int j = jg * 32 + jj;
            const bool allowed = (j == sq) || (vs && (j < last) && (sid[j] == ms));
            const float sc0 = (q[0] * kv[j][0] + q[1] * kv[j][1]) * isq;
            const float sc1 = (q[2] * kv[j][2] + q[3] * kv[j][3]) * isq;
            {
                const float mn = allowed ? fmaxf(m0, sc0) : m0;
                const float c = __expf(m0 - mn);                      // arg <= 0 always
                const float e = allowed ? __expf(sc0 - mn) : 0.0f;    // select: no inf*0
                l0 = l0 * c + e; a00 = a00 * c + e * kv[j][4]; a01 = a01 * c + e * kv[j][5]; m0 = mn;
            }
            {
                const float mn = allowed ? fmaxf(m1, sc1) : m1;
                const float c = __expf(m1 - mn);
                const float e = allowed ? __expf(sc1 - mn) : 0.0f;
                l1 = l1 * c + e; a10 = a10 * c + e * kv[j][6]; a11 = a11 * c + e * kv[j][7]; m1 = mn;
            }
        }
        float* pp = part[lq][jg];
        pp[0] = m0; pp[1] = l0; pp[2] = a00; pp[3] = a01;
        pp[4] = m1; pp[5] = l1; pp[6] = a10; pp[7] = a11;
    }
    __syncthreads();
    if (tid < 32) {
        const int s = chunk * 32 + tid;
        float M0 = -1e30f, L0 = 0.f, A00 = 0.f, A01 = 0.f;
        float M1 = -1e30f, L1 = 0.f, A10 = 0.f, A11 = 0.f;
#pragma unroll
        for (int p = 0; p < 8; ++p) {
            const float* pp = part[tid][p];
            {
                const float mn = fmaxf(M0, pp[0]);
                const float c0 = __expf(M0 - mn), c1 = __expf(pp[0] - mn);   // args <= 0
                L0 = L0 * c0 + pp[1] * c1; A00 = A00 * c0 + pp[2] * c1; A01 = A01 * c0 + pp[3] * c1; M0 = mn;
            }
            {
                const float mn = fmaxf(M1, pp[4]);
                const float c0 = __expf(M1 - mn), c1 = __expf(pp[4] - mn);
                L1 = L1 * c0 + pp[5] * c1; A10 = A10 * c0 + pp[6] * c1; A11 = A11 * c0 + pp[7] * c1; M1 = mn;
            }
        }
        const float4 h = *(const float4*)(bridge + (size_t)(s * 32 + b) * 4);
        const float hb0 = h.x, hb1 = h.y, hb2 = h.z, hb3 = h.w;
        float ao[4] = {A00 / L0, A01 / L0, A10 / L1, A11 / L1};
        float x1[4];
#pragma unroll
        for (int jj = 0; jj < 4; ++jj)
            x1[jj] = ao[0] * Wo[jj] + ao[1] * Wo[4 + jj] + ao[2] * Wo[8 + jj] + ao[3] * Wo[12 + jj];
        x1[0] += hb0; x1[1] += hb1; x1[2] += hb2; x1[3] += hb3;
        float mean = 0.25f * (x1[0] + x1[1] + x1[2] + x1[3]);
        float var = 0.f;
#pragma unroll
        for (int i = 0; i < 4; ++i) { float d = x1[i] - mean; var += d * d; }
        var *= 0.25f;
        const float rs1 = rsqrtf(var + 1e-5f);
        float h1v[4];
#pragma unroll
        for (int i = 0; i < 4; ++i) h1v[i] = (x1[i] - mean) * rs1 * ln1_g[i] + ln1_b[i];
        float o2[4] = {bf2[0], bf2[1], bf2[2], bf2[3]};
#pragma unroll
        for (int kk = 0; kk < 16; ++kk) {
            float t = bf1[kk];
#pragma unroll
            for (int i = 0; i < 4; ++i) t = fmaf(h1v[i], Wf1[i * 16 + kk], t);
            t = fmaxf(t, 0.0f);
#pragma unroll
            for (int jj = 0; jj < 4; ++jj) o2[jj] = fmaf(t, Wf2[kk * 4 + jj], o2[jj]);
        }
        float x2[4];
#pragma unroll
        for (int i = 0; i < 4; ++i) x2[i] = h1v[i] + o2[i];
        float mean2 = 0.25f * (x2[0] + x2[1] + x2[2] + x2[3]);
        float var2 = 0.f;
#pragma unroll
        for (int i = 0; i < 4; ++i) { float d = x2[i] - mean2; var2 += d * d; }
        var2 *= 0.25f;
        const float rs2 = rsqrtf(var2 + 1e-5f);
        float h2v[4];
#pragma unroll
        for (int i = 0; i < 4; ++i) h2v[i] = (x2[i] - mean2) * rs2 * ln2_g[i] + ln2_b[i];
        float* tp = tr_ws + ((size_t)(b * 256 + s)) * 32;
#pragma unroll
        for (int mm = 0; mm < 32; ++mm)
            tp[mm] = bout[mm] + h2v[0] * Wout[mm] + h2v[1] * Wout[32 + mm]
                   + h2v[2] * Wout[64 + mm] + h2v[3] * Wout[96 + mm];
    }
}

// ============================================================================
// K5: atoms: atom_gen = (emb @ Wa + ba)*valid ; seg_interp gather from x
// grid (130, 32), 128 threads (120 active: d*20+i)
// ============================================================================
__global__ __launch_bounds__(128) void k5_atoms(
    const float* __restrict__ x, const float* __restrict__ tr_ws,
    const int* __restrict__ ends_ws, const int* __restrict__ starts_ws,
    const int* __restrict__ nk_ws,
    const float* __restrict__ Wa, const float* __restrict__ ba,
    float* __restrict__ out)
{
    const int a = blockIdx.x;
    const int b = blockIdx.y;
    const int tid = threadIdx.x;
    __shared__ float emb[32];
    const int e = ends_ws[b * 130 + a];
    const int st = starts_ws[b * 130 + a];
    const int nk = nk_ws[b];
    const float valid = (a <= nk) ? 1.0f : 0.0f;
    const int ec = imin(imax(e - 1, 0), 255);
    if (tid < 32) emb[tid] = tr_ws[((size_t)(b * 256 + ec)) * 32 + tid];
    __syncthreads();
    if (tid < 120) {
        float v = ba[tid];
#pragma unroll
        for (int f = 0; f < 32; ++f) v = fmaf(emb[f], Wa[f * 120 + tid], v);
        out[OFF_ATOM + ((size_t)(b * 130 + a)) * 120 + tid] = v * valid;
        const int d = tid / 20, i = tid % 20;
        const int ilen = (e - st) * 400;
        int idx = st * 400 + (i * ilen) / 20;
        idx = imin(imax(idx, 0), 102399);
        const int si = idx / 400, ti = idx % 400;
        const float px = x[(((size_t)b * 256 + si) * 6 + d) * 400 + ti];
        out[OFF_SEG + ((size_t)(b * 130 + a)) * 120 + tid] = px * valid;
    }
}

// ============================================================================
// K6: imu_gen GEMM: relu(bridge@Wd1+bd1) @ Wd2(64x2400) + bd2
// grid (256 n-tiles of 32, 10 m-tiles of 256), 256 threads, 8x4 micro-tile
// ============================================================================
__global__ __launch_bounds__(256) void k6_imu(
    const float* __restrict__ bridge, const float* __restrict__ Wd1,
    const float* __restrict__ bd1, const float* __restrict__ Wd2,
    const float* __restrict__ bd2, float* __restrict__ out)
{
    __shared__ float hl[64 * 32];     // [f][i]
    const int n0 = blockIdx.x * 32;
    const int mb = blockIdx.y;
    const int tid = threadIdx.x;
    for (int e = tid; e < 2048; e += 256) {
        const int f = e >> 5, i = e & 31;
        const float4 br = *(const float4*)(bridge + (size_t)(n0 + i) * 4);
        const float v = bd1[f] + br.x * Wd1[f] + br.y * Wd1[64 + f]
                      + br.z * Wd1[128 + f] + br.w * Wd1[192 + f];
        hl[f * 32 + i] = fmaxf(v, 0.0f);
    }
    __syncthreads();
    const int gm = tid & 63, gn = tid >> 6;
    const int m0 = mb * 256 + gm * 4;
    if (m0 >= 2400) return;
    float acc[8][4];
#pragma unroll
    for (int r = 0; r < 8; ++r)
#pragma unroll
        for (int c = 0; c < 4; ++c) acc[r][c] = 0.f;
#pragma unroll 4
    for (int f = 0; f < 64; ++f) {
        const float4 w4 = *(const float4*)&Wd2[(size_t)f * 2400 + m0];
        const float4 h0 = *(const float4*)&hl[f * 32 + gn * 8];
        const float4 h1 = *(const float4*)&hl[f * 32 + gn * 8 + 4];
        const float hv[8] = {h0.x, h0.y, h0.z, h0.w, h1.x, h1.y, h1.z, h1.w};
        const float wv[4] = {w4.x, w4.y, w4.z, w4.w};
#pragma unroll
        for (int r = 0; r < 8; ++r)
#pragma unroll
            for (int c = 0; c < 4; ++c) acc[r][c] = fmaf(hv[r], wv[c], acc[r][c]);
    }
    const float4 bb = *(const float4*)&bd2[m0];
#pragma unroll
    for (int r = 0; r < 8; ++r) {
        float4 o;
        o.x = acc[r][0] + bb.x; o.y = acc[r][1] + bb.y;
        o.z = acc[r][2] + bb.z; o.w = acc[r][3] + bb.w;
        *(float4*)&out[OFF_IMU + (size_t)(n0 + gn * 8 + r) * 2400 + m0] = o;
    }
}

// ============================================================================
extern "C" void kernel_launch(void* const* d_in, const int* in_sizes, int n_in,
                              void* d_out, int out_size, void* d_ws, size_t ws_size,
                              hipStream_t stream)
{
    const float* x        = (const float*)d_in[0];
    const float* imu_mask = (const float*)d_in[1];
    const int*   imu_len  = (const int*)  d_in[2];
    const float* conv_w   = (const float*)d_in[3];
    const float* conv_b   = (const float*)d_in[4];
    const float* W_b1     = (const float*)d_in[5];
    const float* b_b1     = (const float*)d_in[6];
    const float* W_fc     = (const float*)d_in[7];
    const float* b_fc     = (const float*)d_in[8];
    const float* Wqkv     = (const float*)d_in[9];
    const float* Wo       = (const float*)d_in[10];
    const float* ln1_g    = (const float*)d_in[11];
    const float* ln1_b    = (const float*)d_in[12];
    const float* Wf1      = (const float*)d_in[13];
    const float* bf1      = (const float*)d_in[14];
    const float* Wf2      = (const float*)d_in[15];
    const float* bf2      = (const float*)d_in[16];
    const float* ln2_g    = (const float*)d_in[17];
    const float* ln2_b    = (const float*)d_in[18];
    const float* Wout     = (const float*)d_in[19];
    const float* bout     = (const float*)d_in[20];
    const float* Wd1      = (const float*)d_in[21];
    const float* bd1      = (const float*)d_in[22];
    const float* Wd2      = (const float*)d_in[23];
    const float* bd2      = (const float*)d_in[24];
    const float* Wa       = (const float*)d_in[25];
    const float* ba       = (const float*)d_in[26];

    float* out = (float*)d_out;
    float* wsf = (float*)d_ws;
    int*   wsi = (int*)d_ws;

    float* bridge = wsf + WS_BRIDGE;
    float* tr_ws  = wsf + WS_TR;
    int* segid  = wsi + WS_SEGID;
    int* ends   = wsi + WS_ENDS;
    int* starts = wsi + WS_STARTS;
    int* nk     = wsi + WS_NK;

    k1_conv_bridge<<<2048, 256, 0, stream>>>(x, conv_w, conv_b, W_b1, b_b1, bridge);
    k23_forcast_seg<<<32, 256, 0, stream>>>(bridge, imu_mask, W_fc, b_fc, imu_len,
                                            out, segid, ends, starts, nk);
    k4_attn<<<256, 256, 0, stream>>>(bridge, segid, imu_len, Wqkv, Wo, ln1_g, ln1_b,
                                     Wf1, bf1, Wf2, bf2, ln2_g, ln2_b, Wout, bout, tr_ws);
    k5_atoms<<<dim3(130, 32), 128, 0, stream>>>(x, tr_ws, ends, starts, nk, Wa, ba, out);
    k6_imu<<<dim3(256, 10), 256, 0, stream>>>(bridge, Wd1, bd1, Wd2, bd2, out);
}

// Round 6
// 118.756 us; speedup vs baseline: 1.4259x; 1.0351x over previous
//
#include <hip/hip_runtime.h>
#include <math.h>

// ---- output layout ----
#define OFF_IMU  0
#define OFF_ATOM 19660800
#define OFF_SEG  20160000
#define OFF_FC   20659200
#define OFF_FL   20691968

// ---- ws layout (4-byte elements) ----
#define WS_BRIDGE 0        // 32768 floats  (8192 x 4)
#define WS_TR     32768    // 262144 floats (8192 x 32)
#define WS_SEGID  294912   // 8192 ints
#define WS_ENDS   303104   // 4160 ints
#define WS_STARTS 307264   // 4160 ints
#define WS_NK     311424   // 32 ints

static __device__ __forceinline__ int imin(int a, int b) { return a < b ? a : b; }
static __device__ __forceinline__ int imax(int a, int b) { return a > b ? a : b; }

// ============================================================================
// K1: conv1d(6->32,k=3,VALID) + ReLU + half-mean-pool + bridge sigmoid MLP
// 2048 blocks x 256 threads; 4 samples/block, one WAVE per sample.
// Lane l: oc = l&31, half = l>>5. Lane walks its half's 50 4-chunks.
// ROLLING WINDOW + IMMEDIATE OFFSETS: 7 groups x 7 unrolled chunks, one base
// pointer advanced per group; all ds_read_b128 use compile-time offsets and
// each x element is read exactly once per wave. No b64 reads in the loop.
// ============================================================================
__global__ __launch_bounds__(256) void k1_conv_bridge(
    const float* __restrict__ x, const float* __restrict__ conv_w,
    const float* __restrict__ conv_b, const float* __restrict__ W_b1,
    const float* __restrict__ b_b1, float* __restrict__ bridge)
{
    __shared__ __align__(16) float xs[4][2424];  // [smp][ic*404 + t]; 400..403 zeroed
    __shared__ float pooledL[4][64];
    const int tid = threadIdx.x;
    const int n0 = blockIdx.x * 4;

    const int wv = tid >> 6;           // wave = sample
    const int l  = tid & 63;
    const int oc = l & 31;
    const int hg = l >> 5;             // pooling half

    // per-lane weights (one oc): 18 + bias, loaded once from global (L2-hot)
    float w[18];
    {
        const float* wp = conv_w + oc * 18;
#pragma unroll
        for (int j = 0; j < 18; ++j) w[j] = wp[j];
    }
    const float cb = conv_b[oc];

    // stage 4 samples of x into LDS (coalesced float4)
    const float* xn = x + (size_t)n0 * 2400;
    for (int i = tid; i < 2400; i += 256) {
        const float4 v = ((const float4*)xn)[i];
        const int smp = i / 600;
        const int r = i - smp * 600;
        const int ic = r / 100, t4 = (r - ic * 100) * 4;
        *(float4*)&xs[smp][ic * 404 + t4] = v;
    }
    if (tid < 96) {                    // zero pads so tail multiplies stay finite
        const int smp = tid / 24, r = tid - smp * 24;
        xs[smp][(r >> 2) * 404 + 400 + (r & 3)] = 0.0f;
    }
    __syncthreads();

    const float* rb = &xs[wv][hg * 200];   // row ic at rb + ic*404 (imm-foldable)
    float accMain = 0.0f;

    float4 cur[6];
#pragma unroll
    for (int ic = 0; ic < 6; ++ic)
        cur[ic] = *(const float4*)(rb + ic * 404);      // x[t0..t0+3]

    // 49 body chunks = 7 groups x 7 unrolled; rolling window, imm offsets
    for (int g = 0; g < 7; ++g) {
#pragma unroll
        for (int u = 0; u < 7; ++u) {
            float s0 = cb, s1 = cb, s2 = cb, s3 = cb;
#pragma unroll
            for (int ic = 0; ic < 6; ++ic) {
                const float4 nxt = *(const float4*)(rb + ic * 404 + (u + 1) * 4);
                const float x0 = cur[ic].x, x1 = cur[ic].y, x2 = cur[ic].z,
                            x3 = cur[ic].w, x4 = nxt.x, x5 = nxt.y;
                const float w0 = w[ic * 3 + 0], w1 = w[ic * 3 + 1], w2 = w[ic * 3 + 2];
                s0 = fmaf(w0, x0, s0); s0 = fmaf(w1, x1, s0); s0 = fmaf(w2, x2, s0);
                s1 = fmaf(w0, x1, s1); s1 = fmaf(w1, x2, s1); s1 = fmaf(w2, x3, s1);
                s2 = fmaf(w0, x2, s2); s2 = fmaf(w1, x3, s2); s2 = fmaf(w2, x4, s2);
                s3 = fmaf(w0, x3, s3); s3 = fmaf(w1, x4, s3); s3 = fmaf(w2, x5, s3);
                cur[ic] = nxt;                            // SSA rename
            }
            accMain += fmaxf(s0, 0.0f) + fmaxf(s1, 0.0f)
                     + fmaxf(s2, 0.0f) + fmaxf(s3, 0.0f);
        }
        rb += 28;                      // 7 chunks x 4 floats
    }
    // after loop: rb = rowbase + 196, cur[ic] = x[196..199] of row ic

    // tail chunk: hg0 t=196..199 (196-198 half0, 199 -> half1 extra);
    //             hg1 t=396..399 (396,397 valid; 398,399 masked; pad=0)
    float accExtra;
    {
        float s0 = cb, s1 = cb, s2 = cb, s3 = cb;
#pragma unroll
        for (int ic = 0; ic < 6; ++ic) {
            const float2 n2 = *(const float2*)(rb + ic * 404 + 4);  // x[200,201]
            const float x0 = cur[ic].x, x1 = cur[ic].y, x2 = cur[ic].z,
                        x3 = cur[ic].w, x4 = n2.x, x5 = n2.y;
            const float w0 = w[ic * 3 + 0], w1 = w[ic * 3 + 1], w2 = w[ic * 3 + 2];
            s0 = fmaf(w0, x0, s0); s0 = fmaf(w1, x1, s0); s0 = fmaf(w2, x2, s0);
            s1 = fmaf(w0, x1, s1); s1 = fmaf(w1, x2, s1); s1 = fmaf(w2, x3, s1);
            s2 = fmaf(w0, x2, s2); s2 = fmaf(w1, x3, s2); s2 = fmaf(w2, x4, s2);
            s3 = fmaf(w0, x3, s3); s3 = fmaf(w1, x4, s3); s3 = fmaf(w2, x5, s3);
        }
        const float r0 = fmaxf(s0, 0.0f), r1 = fmaxf(s1, 0.0f);
        const float r2 = fmaxf(s2, 0.0f), r3 = fmaxf(s3, 0.0f);
        accMain += r0 + r1 + (hg ? 0.0f : r2);   // hg1: t=398,399 invalid
        accExtra = hg ? 0.0f : r3;               // hg0: t=199 belongs to half1
    }

    // boundary fix: half1 total = accMain(hg1) + accExtra(hg0 partner)
    const float extraP = __shfl_xor(accExtra, 32);
    const float h = (hg ? (accMain + extraP) : accMain) * (1.0f / 199.0f);
    pooledL[wv][(oc << 1) | hg] = h;
    __syncthreads();

    // bridge MLP: all 256 threads; sample = tid>>6, feature f = tid&63
    {
        const int s2 = tid >> 6, f = tid & 63;
        const float v = pooledL[s2][f];
        const float4 wb = *(const float4*)(W_b1 + f * 4);
        float p0 = v * wb.x, p1 = v * wb.y, p2 = v * wb.z, p3 = v * wb.w;
#pragma unroll
        for (int off = 1; off < 64; off <<= 1) {
            p0 += __shfl_xor(p0, off, 64);
            p1 += __shfl_xor(p1, off, 64);
            p2 += __shfl_xor(p2, off, 64);
            p3 += __shfl_xor(p3, off, 64);
        }
        if (f == 0) {
            float* bp = bridge + (size_t)(n0 + s2) * 4;
            bp[0] = 1.0f / (1.0f + __expf(-(p0 + b_b1[0])));
            bp[1] = 1.0f / (1.0f + __expf(-(p1 + b_b1[1])));
            bp[2] = 1.0f / (1.0f + __expf(-(p2 + b_b1[2])));
            bp[3] = 1.0f / (1.0f + __expf(-(p3 + b_b1[3])));
        }
    }
}

// ============================================================================
// K23: forcast + masked floss (to d_out) fused with per-batch segmentation.
// one block per b (32 x 256)
// ============================================================================
__global__ __launch_bounds__(256) void k23_forcast_seg(
    const float* __restrict__ bridge, const float* __restrict__ imu_mask,
    const float* __restrict__ W_fc, const float* __restrict__ b_fc,
    const int* __restrict__ imu_len, float* __restrict__ out,
    int* __restrict__ segid_ws, int* __restrict__ ends_ws,
    int* __restrict__ starts_ws, int* __restrict__ nk_ws)
{
    const int b = blockIdx.x, tid = threadIdx.x;
    const int n = b * 256 + tid;
    __shared__ float fl[256];
    __shared__ float sel[256];
    __shared__ float sp[256];
    __shared__ int pk[256];
    __shared__ int sc[2][256];
    __shared__ int kpl[256];

    // ---- forcast + floss ----
    float sh[4], cur[4];
#pragma unroll
    for (int j = 0; j < 4; ++j) {
        sh[j] = (tid == 0) ? 0.0f : bridge[(n - 1) * 4 + j];
        cur[j] = bridge[n * 4 + j];
    }
    const float fm = ((tid == 0) ? 0.0f : 1.0f) * imu_mask[n];
    float flv = 0.0f;
#pragma unroll
    for (int j = 0; j < 4; ++j) {
        float f = b_fc[j];
#pragma unroll
        for (int i = 0; i < 4; ++i) f = fmaf(sh[i], W_fc[i * 4 + j], f);
        out[OFF_FC + n * 4 + j] = f;
        const float d = (f - cur[j]) * fm;
        flv = fmaf(d, d, flv);
    }
    flv *= 0.25f;
    const bool lm = (tid >= 2) && (tid < 254);
    flv = (flv > 0.001f && lm) ? flv : 0.0f;
    out[OFF_FL + n] = flv;

    // ---- segmentation ----
    fl[tid] = flv;
    sp[tid] = 0.0f;
    __syncthreads();
    if (tid < 64) {                       // sel: windows of 4, first-max
        const int base = tid * 4;
        float m = fl[base]; int idx = 0;
#pragma unroll
        for (int i = 1; i < 4; ++i) { float v = fl[base + i]; if (v > m) { m = v; idx = i; } }
#pragma unroll
        for (int i = 0; i < 4; ++i) sel[base + i] = (i == idx) ? m : 0.0f;
    }
    __syncthreads();
    if (tid < 63) {                       // sel2 on sel[2:254), 63 windows of 4
        const int base = 2 + tid * 4;
        float m = sel[base]; int idx = 0;
#pragma unroll
        for (int i = 1; i < 4; ++i) { float v = sel[base + i]; if (v > m) { m = v; idx = i; } }
        sp[base + idx] = (m > 0.0f) ? 1.0f : 0.0f;
    }
    __syncthreads();
    int last = (int)rintf((float)imu_len[b] * (1.0f / 256.0f));  // half-even
    last = imin(imax(last, 2), 256);
    const int point = ((sp[tid] > 0.0f) && (tid < last)) ? 1 : 0;
    pk[tid] = point;
    __syncthreads();
    const int pnext = (tid < 255) ? pk[tid + 1] : 0;
    const int bnd = pnext | ((tid + 1 == last) ? 1 : 0);
    const int kept = (point && !bnd) ? 1 : 0;
    __syncthreads();
    sc[0][tid] = kept;
    __syncthreads();
    int src = 0;                          // Hillis-Steele inclusive scan
    for (int off = 1; off < 256; off <<= 1) {
        const int v = sc[src][tid] + ((tid >= off) ? sc[src][tid - off] : 0);
        sc[src ^ 1][tid] = v;
        __syncthreads();
        src ^= 1;
    }
    const int myid = sc[src][tid];
    segid_ws[b * 256 + tid] = myid;
    const int nk = sc[src][255];
    if (kept) kpl[myid - 1] = tid;
    __syncthreads();
    if (tid < 130) {
        ends_ws[b * 130 + tid] = (tid < nk) ? kpl[tid] : last;
        starts_ws[b * 130 + tid] = (tid == 0) ? 0 : ((tid - 1 < nk) ? kpl[tid - 1] : last);
    }
    if (tid == 0) nk_ws[b] = nk;
}

// ============================================================================
// K4: segment-masked attention (DM=4, 2 heads) + transformer block + tr_out
// grid 256 = (b, 32-query chunk), 256 threads: 8 j-groups x 32 queries,
// LDS online-softmax merge. NOTE hb[b,s] = bridge[s*32 + b] (scrambled).
// exp() only evaluated with argument <= 0 (select, never mask-multiply).
// ============================================================================
__global__ __launch_bounds__(256) void k4_attn(
    const float* __restrict__ bridge, const int* __restrict__ segid_ws,
    const int* __restrict__ imu_len,
    const float* __restrict__ Wqkv, const float* __restrict__ Wo,
    const float* __restrict__ ln1_g, const float* __restrict__ ln1_b,
    const float* __restrict__ Wf1, const float* __restrict__ bf1,
    const float* __restrict__ Wf2, const float* __restrict__ bf2,
    const float* __restrict__ ln2_g, const float* __restrict__ ln2_b,
    const float* __restrict__ Wout, const float* __restrict__ bout,
    float* __restrict__ tr_ws)
{
    const int b = blockIdx.x >> 3;
    const int chunk = blockIdx.x & 7;
    const int tid = threadIdx.x;
    __shared__ float kv[256][8];
    __shared__ int sid[256];
    __shared__ float part[32][8][8];
    {
        const int s2 = tid;
        const float4 h = *(const float4*)(bridge + (size_t)(s2 * 32 + b) * 4);
#pragma unroll
        for (int e = 0; e < 4; ++e) {
            kv[s2][e]     = h.x * Wqkv[16 + e] + h.y * Wqkv[20 + e] + h.z * Wqkv[24 + e] + h.w * Wqkv[28 + e];
            kv[s2][4 + e] = h.x * Wqkv[32 + e] + h.y * Wqkv[36 + e] + h.z * Wqkv[40 + e] + h.w * Wqkv[44 + e];
        }
        sid[s2] = segid_ws[b * 256 + s2];
    }
    __syncthreads();
    int last = (int)rintf((float)imu_len[b] * (1.0f / 256.0f));
    last = imin(imax(last, 2), 256);
    const int lq = tid & 31;
    const int jg = tid >> 5;
    const int sq = chunk * 32 + lq;
    {
        const float4 h = *(const float4*)(bridge + (size_t)(sq * 32 + b) * 4);
        float q[4];
#pragma unroll
        for (int e = 0; e < 4; ++e)
            q[e] = h.x * Wqkv[e] + h.y * Wqkv[4 + e] + h.z * Wqkv[8 + e] + h.w * Wqkv[12 + e];
        const bool vs = sq < last;
        const int ms = sid[sq];
        const float isq = 0.70710678118654752f;
        float m0 = -1e30f, l0 = 0.f, a00 = 0.f, a01 = 0.f;
        float m1 = -1e30f, l1 = 0.f, a10 = 0.f, a11 = 0.f;
#pragma unroll 4
        for (int jj = 0; jj < 32; ++jj) {
            const int j = jg * 32 + jj;
            const bool allowed = (j == sq) || (vs && (j < last) && (sid[j] == ms));
            const float sc0 = (q[0] * kv[j][0] + q[1] * kv[j][1]) * isq;
            const float sc1 = (q[2] * kv[j][2] + q[3] * kv[j][3]) * isq;
            {
                const float mn = allowed ? fmaxf(m0, sc0) : m0;
                const float c = __expf(m0 - mn);                      // arg <= 0 always
                const float e = allowed ? __expf(sc0 - mn) : 0.0f;    // select: no inf*0
                l0 = l0 * c + e; a00 = a00 * c + e * kv[j][4]; a01 = a01 * c + e * kv[j][5]; m0 = mn;
            }
            {
                const float mn = allowed ? fmaxf(m1, sc1) : m1;
                const float c = __expf(m1 - mn);
                const float e = allowed ? __expf(sc1 - mn) : 0.0f;
                l1 = l1 * c + e; a10 = a10 * c + e * kv[j][6]; a11 = a11 * c + e * kv[j][7]; m1 = mn;
            }
        }
        float* pp = part[lq][jg];
        pp[0] = m0; pp[1] = l0; pp[2] = a00; pp[3] = a01;
        pp[4] = m1; pp[5] = l1; pp[6] = a10; pp[7] = a11;
    }
    __syncthreads();
    if (tid < 32) {
        const int s = chunk * 32 + tid;
        float M0 = -1e30f, L0 = 0.f, A00 = 0.f, A01 = 0.f;
        float M1 = -1e30f, L1 = 0.f, A10 = 0.f, A11 = 0.f;
#pragma unroll
        for (int p = 0; p < 8; ++p) {
            const float* pp = part[tid][p];
            {
                const float mn = fmaxf(M0, pp[0]);
                const float c0 = __expf(M0 - mn), c1 = __expf(pp[0] - mn);   // args <= 0
                L0 = L0 * c0 + pp[1] * c1; A00 = A00 * c0 + pp[2] * c1; A01 = A01 * c0 + pp[3] * c1; M0 = mn;
            }
            {
                const float mn = fmaxf(M1, pp[4]);
                const float c0 = __expf(M1 - mn), c1 = __expf(pp[4] - mn);
                L1 = L1 * c0 + pp[5] * c1; A10 = A10 * c0 + pp[6] * c1; A11 = A11 * c0 + pp[7] * c1; M1 = mn;
            }
        }
        const float4 h = *(const float4*)(bridge + (size_t)(s * 32 + b) * 4);
        const float hb0 = h.x, hb1 = h.y, hb2 = h.z, hb3 = h.w;
        float ao[4] = {A00 / L0, A01 / L0, A10 / L1, A11 / L1};
        float x1[4];
#pragma unroll
        for (int jj = 0; jj < 4; ++jj)
            x1[jj] = ao[0] * Wo[jj] + ao[1] * Wo[4 + jj] + ao[2] * Wo[8 + jj] + ao[3] * Wo[12 + jj];
        x1[0] += hb0; x1[1] += hb1; x1[2] += hb2; x1[3] += hb3;
        float mean = 0.25f * (x1[0] + x1[1] + x1[2] + x1[3]);
        float var = 0.f;
#pragma unroll
        for (int i = 0; i < 4; ++i) { float d = x1[i] - mean; var += d * d; }
        var *= 0.25f;
        const float rs1 = rsqrtf(var + 1e-5f);
        float h1v[4];
#pragma unroll
        for (int i = 0; i < 4; ++i) h1v[i] = (x1[i] - mean) * rs1 * ln1_g[i] + ln1_b[i];
        float o2[4] = {bf2[0], bf2[1], bf2[2], bf2[3]};
#pragma unroll
        for (int kk = 0; kk < 16; ++kk) {
            float t = bf1[kk];
#pragma unroll
            for (int i = 0; i < 4; ++i) t = fmaf(h1v[i], Wf1[i * 16 + kk], t);
            t = fmaxf(t, 0.0f);
#pragma unroll
            for (int jj = 0; jj < 4; ++jj) o2[jj] = fmaf(t, Wf2[kk * 4 + jj], o2[jj]);
        }
        float x2[4];
#pragma unroll
        for (int i = 0; i < 4; ++i) x2[i] = h1v[i] + o2[i];
        float mean2 = 0.25f * (x2[0] + x2[1] + x2[2] + x2[3]);
        float var2 = 0.f;
#pragma unroll
        for (int i = 0; i < 4; ++i) { float d = x2[i] - mean2; var2 += d * d; }
        var2 *= 0.25f;
        const float rs2 = rsqrtf(var2 + 1e-5f);
        float h2v[4];
#pragma unroll
        for (int i = 0; i < 4; ++i) h2v[i] = (x2[i] - mean2) * rs2 * ln2_g[i] + ln2_b[i];
        float* tp = tr_ws + ((size_t)(b * 256 + s)) * 32;
#pragma unroll
        for (int mm = 0; mm < 32; ++mm)
            tp[mm] = bout[mm] + h2v[0] * Wout[mm] + h2v[1] * Wout[32 + mm]
                   + h2v[2] * Wout[64 + mm] + h2v[3] * Wout[96 + mm];
    }
}

// ============================================================================
// K5: atoms: atom_gen = (emb @ Wa + ba)*valid ; seg_interp gather from x
// grid (130, 32), 128 threads (120 active: d*20+i)
// ============================================================================
__global__ __launch_bounds__(128) void k5_atoms(
    const float* __restrict__ x, const float* __restrict__ tr_ws,
    const int* __restrict__ ends_ws, const int* __restrict__ starts_ws,
    const int* __restrict__ nk_ws,
    const float* __restrict__ Wa, const float* __restrict__ ba,
    float* __restrict__ out)
{
    const int a = blockIdx.x;
    const int b = blockIdx.y;
    const int tid = threadIdx.x;
    __shared__ float emb[32];
    const int e = ends_ws[b * 130 + a];
    const int st = starts_ws[b * 130 + a];
    const int nk = nk_ws[b];
    const float valid = (a <= nk) ? 1.0f : 0.0f;
    const int ec = imin(imax(e - 1, 0), 255);
    if (tid < 32) emb[tid] = tr_ws[((size_t)(b * 256 + ec)) * 32 + tid];
    __syncthreads();
    if (tid < 120) {
        float v = ba[tid];
#pragma unroll
        for (int f = 0; f < 32; ++f) v = fmaf(emb[f], Wa[f * 120 + tid], v);
        out[OFF_ATOM + ((size_t)(b * 130 + a)) * 120 + tid] = v * valid;
        const int d = tid / 20, i = tid % 20;
        const int ilen = (e - st) * 400;
        int idx = st * 400 + (i * ilen) / 20;
        idx = imin(imax(idx, 0), 102399);
        const int si = idx / 400, ti = idx % 400;
        const float px = x[(((size_t)b * 256 + si) * 6 + d) * 400 + ti];
        out[OFF_SEG + ((size_t)(b * 130 + a)) * 120 + tid] = px * valid;
    }
}

// ============================================================================
// K6: imu_gen GEMM: relu(bridge@Wd1+bd1) @ Wd2(64x2400) + bd2
// grid (256 n-tiles of 32, 10 m-tiles of 256), 256 threads, 8x4 micro-tile
// ============================================================================
__global__ __launch_bounds__(256) void k6_imu(
    const float* __restrict__ bridge, const float* __restrict__ Wd1,
    const float* __restrict__ bd1, const float* __restrict__ Wd2,
    const float* __restrict__ bd2, float* __restrict__ out)
{
    __shared__ float hl[64 * 32];     // [f][i]
    const int n0 = blockIdx.x * 32;
    const int mb = blockIdx.y;
    const int tid = threadIdx.x;
    for (int e = tid; e < 2048; e += 256) {
        const int f = e >> 5, i = e & 31;
        const float4 br = *(const float4*)(bridge + (size_t)(n0 + i) * 4);
        const float v = bd1[f] + br.x * Wd1[f] + br.y * Wd1[64 + f]
                      + br.z * Wd1[128 + f] + br.w * Wd1[192 + f];
        hl[f * 32 + i] = fmaxf(v, 0.0f);
    }
    __syncthreads();
    const int gm = tid & 63, gn = tid >> 6;
    const int m0 = mb * 256 + gm * 4;
    if (m0 >= 2400) return;
    float acc[8][4];
#pragma unroll
    for (int r = 0; r < 8; ++r)
#pragma unroll
        for (int c = 0; c < 4; ++c) acc[r][c] = 0.f;
#pragma unroll 4
    for (int f = 0; f < 64; ++f) {
        const float4 w4 = *(const float4*)&Wd2[(size_t)f * 2400 + m0];
        const float4 h0 = *(const float4*)&hl[f * 32 + gn * 8];
        const float4 h1 = *(const float4*)&hl[f * 32 + gn * 8 + 4];
        const float hv[8] = {h0.x, h0.y, h0.z, h0.w, h1.x, h1.y, h1.z, h1.w};
        const float wv[4] = {w4.x, w4.y, w4.z, w4.w};
#pragma unroll
        for (int r = 0; r < 8; ++r)
#pragma unroll
            for (int c = 0; c < 4; ++c) acc[r][c] = fmaf(hv[r], wv[c], acc[r][c]);
    }
    const float4 bb = *(const float4*)&bd2[m0];
#pragma unroll
    for (int r = 0; r < 8; ++r) {
        float4 o;
        o.x = acc[r][0] + bb.x; o.y = acc[r][1] + bb.y;
        o.z = acc[r][2] + bb.z; o.w = acc[r][3] + bb.w;
        *(float4*)&out[OFF_IMU + (size_t)(n0 + gn * 8 + r) * 2400 + m0] = o;
    }
}

// ============================================================================
extern "C" void kernel_launch(void* const* d_in, const int* in_sizes, int n_in,
                              void* d_out, int out_size, void* d_ws, size_t ws_size,
                              hipStream_t stream)
{
    const float* x        = (const float*)d_in[0];
    const float* imu_mask = (const float*)d_in[1];
    const int*   imu_len  = (const int*)  d_in[2];
    const float* conv_w   = (const float*)d_in[3];
    const float* conv_b   = (const float*)d_in[4];
    const float* W_b1     = (const float*)d_in[5];
    const float* b_b1     = (const float*)d_in[6];
    const float* W_fc     = (const float*)d_in[7];
    const float* b_fc     = (const float*)d_in[8];
    const float* Wqkv     = (const float*)d_in[9];
    const float* Wo       = (const float*)d_in[10];
    const float* ln1_g    = (const float*)d_in[11];
    const float* ln1_b    = (const float*)d_in[12];
    const float* Wf1      = (const float*)d_in[13];
    const float* bf1      = (const float*)d_in[14];
    const float* Wf2      = (const float*)d_in[15];
    const float* bf2      = (const float*)d_in[16];
    const float* ln2_g    = (const float*)d_in[17];
    const float* ln2_b    = (const float*)d_in[18];
    const float* Wout     = (const float*)d_in[19];
    const float* bout     = (const float*)d_in[20];
    const float* Wd1      = (const float*)d_in[21];
    const float* bd1      = (const float*)d_in[22];
    const float* Wd2      = (const float*)d_in[23];
    const float* bd2      = (const float*)d_in[24];
    const float* Wa       = (const float*)d_in[25];
    const float* ba       = (const float*)d_in[26];

    float* out = (float*)d_out;
    float* wsf = (float*)d_ws;
    int*   wsi = (int*)d_ws;

    float* bridge = wsf + WS_BRIDGE;
    float* tr_ws  = wsf + WS_TR;
    int* segid  = wsi + WS_SEGID;
    int* ends   = wsi + WS_ENDS;
    int* starts = wsi + WS_STARTS;
    int* nk     = wsi + WS_NK;

    k1_conv_bridge<<<2048, 256, 0, stream>>>(x, conv_w, conv_b, W_b1, b_b1, bridge);
    k23_forcast_seg<<<32, 256, 0, stream>>>(bridge, imu_mask, W_fc, b_fc, imu_len,
                                            out, segid, ends, starts, nk);
    k4_attn<<<256, 256, 0, stream>>>(bridge, segid, imu_len, Wqkv, Wo, ln1_g, ln1_b,
                                     Wf1, bf1, Wf2, bf2, ln2_g, ln2_b, Wout, bout, tr_ws);
    k5_atoms<<<dim3(130, 32), 128, 0, stream>>>(x, tr_ws, ends, starts, nk, Wa, ba, out);
    k6_imu<<<dim3(256, 10), 256, 0, stream>>>(bridge, Wd1, bd1, Wd2, bd2, out);
}